// Round 9
// baseline (424.052 us; speedup 1.0000x reference)
//
#include <hip/hip_runtime.h>
#include <hip/hip_bf16.h>

#define N_NODES 100000
#define N_EDGES 1600000
#define D 128

typedef __attribute__((ext_vector_type(8))) short short8;
typedef __attribute__((ext_vector_type(4))) float f32x4;

__device__ __forceinline__ float bf2f(unsigned short u) {
    union { unsigned int i; float f; } c; c.i = ((unsigned int)u) << 16; return c.f;
}
__device__ __forceinline__ unsigned short f2bf(float f) {
    union { float f; unsigned int i; } c; c.f = f;
    unsigned int u = c.i;
    return (unsigned short)((u + 0x7fffu + ((u >> 16) & 1u)) >> 16);   // RNE
}

// ---------------- fused preprocessing: histogram + casts ----------------
// Blocks [0,6250): 8-way privatized degree histogram (atomic-return = rank).
// These are fabric-atomic-bound with idle VALU/HBM (r7: 0.5% VALU, 12% HBM),
// so blocks [6250,12500) overlap the x->bf16 cast and [12500,12504) the
// weight transpose+cast in their shadow.

__global__ __launch_bounds__(256) void k_pre(
    const int* __restrict__ dst, int* __restrict__ deg8, int* __restrict__ rank,
    const float* __restrict__ x, unsigned short* __restrict__ xb,
    const float* __restrict__ W0, const float* __restrict__ W1,
    const float* __restrict__ W2, const float* __restrict__ W3,
    unsigned short* __restrict__ T)
{
    int b = blockIdx.x;
    if (b < 6250) {                       // histogram: 6250*256 == N_EDGES exact
        int e = b * 256 + threadIdx.x;
        int c = b & 7;
        rank[e] = atomicAdd(&deg8[c * N_NODES + dst[e]], 1);
    } else if (b < 12500) {               // cast_x: 6250*256*8 == N_NODES*D exact
        int i = (b - 6250) * 256 + threadIdx.x;
        int base = i * 8;
        float4 a = *(const float4*)&x[base];
        float4 v = *(const float4*)&x[base + 4];
        uint4 o;
        o.x = (unsigned)f2bf(a.x) | ((unsigned)f2bf(a.y) << 16);
        o.y = (unsigned)f2bf(a.z) | ((unsigned)f2bf(a.w) << 16);
        o.z = (unsigned)f2bf(v.x) | ((unsigned)f2bf(v.y) << 16);
        o.w = (unsigned)f2bf(v.z) | ((unsigned)f2bf(v.w) << 16);
        *(uint4*)&xb[base] = o;
    } else {                              // cast_w: W[k][n] fp32 -> T[n][k] bf16
        int m = b - 12500;
        const float* W = (m == 0) ? W0 : (m == 1) ? W1 : (m == 2) ? W2 : W3;
        unsigned short* Tm = T + m * D * D;
        int n = threadIdx.x & 127;
        int kh = (threadIdx.x >> 7) * 64;
        for (int k = kh; k < kh + 64; ++k)
            Tm[n * D + k] = f2bf(W[k * D + n]);
    }
}

// fused: deg = sum(deg8 copies); per-block exclusive scan -> offsP, bsum
__global__ void k_scan1(const int* __restrict__ deg8, int* __restrict__ deg,
                        int* __restrict__ offsP, int* __restrict__ bsum) {
    __shared__ int s[256];
    int i = blockIdx.x * 256 + threadIdx.x;
    int v = 0;
    if (i < N_NODES) {
#pragma unroll
        for (int c = 0; c < 8; ++c) v += deg8[c * N_NODES + i];
        deg[i] = v;
    }
    s[threadIdx.x] = v;
    __syncthreads();
    for (int off = 1; off < 256; off <<= 1) {
        int t = (threadIdx.x >= off) ? s[threadIdx.x - off] : 0;
        __syncthreads();
        s[threadIdx.x] += t;
        __syncthreads();
    }
    if (i < N_NODES) offsP[i] = s[threadIdx.x] - v;
    if (threadIdx.x == 255) bsum[blockIdx.x] = s[255];
}

__global__ void k_scan2(int* __restrict__ bsum, int nb) {
    __shared__ int s[512];
    int t = threadIdx.x;
    int v = (t < nb) ? bsum[t] : 0;
    s[t] = v;
    __syncthreads();
    for (int off = 1; off < 512; off <<= 1) {
        int u = (t >= off) ? s[t - off] : 0;
        __syncthreads();
        s[t] += u;
        __syncthreads();
    }
    if (t < nb) bsum[t] = s[t] - v;
}

__global__ __launch_bounds__(256) void k_offs8(const int* __restrict__ offsP,
                                               const int* __restrict__ bsum,
                                               const int* __restrict__ deg8,
                                               int* __restrict__ offs,
                                               int* __restrict__ offs8) {
    int i = blockIdx.x * 256 + threadIdx.x;
    if (i < N_NODES) {
        int o = offsP[i] + bsum[blockIdx.x];
        offs[i] = o;
#pragma unroll
        for (int c = 0; c < 8; ++c) {
            offs8[c * N_NODES + i] = o;
            o += deg8[c * N_NODES + i];
        }
    }
}

__global__ __launch_bounds__(256) void k_place(const int* __restrict__ src,
                                               const int* __restrict__ dst,
                                               const int* __restrict__ rank,
                                               const int* __restrict__ offs8,
                                               int* __restrict__ csr) {
    int e = blockIdx.x * 256 + threadIdx.x;   // same geometry as k_pre histogram
    int c = blockIdx.x & 7;
    int d = dst[e];
    __builtin_nontemporal_store(src[e], &csr[offs8[c * N_NODES + d] + rank[e]]);
}

// ---------------- mean aggregation (half-wave per edge, uint2 loads) ----------------

__global__ __launch_bounds__(256) void k_aggr_b(
    const unsigned short* __restrict__ xb, const int* __restrict__ offs,
    const int* __restrict__ deg, const int* __restrict__ csr,
    unsigned short* __restrict__ aggrb)
{
    int wave = threadIdx.x >> 6;
    int l = threadIdx.x & 63;
    int half = l >> 5;            // which edge of the pair
    int li = l & 31;              // feature quad: features [li*4, li*4+4)
    int node = blockIdx.x * 4 + wave;
    if (node >= N_NODES) return;
    int start = offs[node];
    int d = deg[node];
    float a0 = 0.f, a1 = 0.f, a2 = 0.f, a3 = 0.f;
    int e = 0;
    for (; e + 8 <= d; e += 8) {
        int j0 = csr[start + e + 0 + half];
        int j1 = csr[start + e + 2 + half];
        int j2 = csr[start + e + 4 + half];
        int j3 = csr[start + e + 6 + half];
        uint2 v0 = *(const uint2*)&xb[j0 * D + li * 4];
        uint2 v1 = *(const uint2*)&xb[j1 * D + li * 4];
        uint2 v2 = *(const uint2*)&xb[j2 * D + li * 4];
        uint2 v3 = *(const uint2*)&xb[j3 * D + li * 4];
        a0 += (bf2f(v0.x & 0xffff) + bf2f(v1.x & 0xffff)) + (bf2f(v2.x & 0xffff) + bf2f(v3.x & 0xffff));
        a1 += (bf2f(v0.x >> 16)    + bf2f(v1.x >> 16))    + (bf2f(v2.x >> 16)    + bf2f(v3.x >> 16));
        a2 += (bf2f(v0.y & 0xffff) + bf2f(v1.y & 0xffff)) + (bf2f(v2.y & 0xffff) + bf2f(v3.y & 0xffff));
        a3 += (bf2f(v0.y >> 16)    + bf2f(v1.y >> 16))    + (bf2f(v2.y >> 16)    + bf2f(v3.y >> 16));
    }
    for (; e + 2 <= d; e += 2) {
        int j = csr[start + e + half];
        uint2 v = *(const uint2*)&xb[j * D + li * 4];
        a0 += bf2f(v.x & 0xffff); a1 += bf2f(v.x >> 16);
        a2 += bf2f(v.y & 0xffff); a3 += bf2f(v.y >> 16);
    }
    if ((d & 1) && half == 0) {   // odd tail: half 0 only
        int j = csr[start + d - 1];
        uint2 v = *(const uint2*)&xb[j * D + li * 4];
        a0 += bf2f(v.x & 0xffff); a1 += bf2f(v.x >> 16);
        a2 += bf2f(v.y & 0xffff); a3 += bf2f(v.y >> 16);
    }
    a0 += __shfl_xor(a0, 32, 64);
    a1 += __shfl_xor(a1, 32, 64);
    a2 += __shfl_xor(a2, 32, 64);
    a3 += __shfl_xor(a3, 32, 64);
    if (half == 0) {
        float inv = 1.f / (float)(d > 0 ? d : 1);
        uint2 o;
        o.x = (unsigned)f2bf(a0 * inv) | ((unsigned)f2bf(a1 * inv) << 16);
        o.y = (unsigned)f2bf(a2 * inv) | ((unsigned)f2bf(a3 * inv) << 16);
        *(uint2*)&aggrb[node * D + li * 4] = o;
    }
}

// ---------------- MFMA GEMM: out = A@Wl + B@Wr + bias ----------------
// BM=128 rows/block, 4 waves x 32 rows (2 A-frags reused over 8 B-frags).

template<int OUT_BF16, int RELU>
__global__ __launch_bounds__(256) void k_gemm_mfma(
    const unsigned short* __restrict__ Ab,   // aggr bf16 [N][D]
    const unsigned short* __restrict__ Bb,   // x/h  bf16 [N][D] (may alias out when OUT_BF16)
    const unsigned short* __restrict__ Wlt,  // [n][k] bf16
    const unsigned short* __restrict__ Wrt,  // [n][k] bf16
    const float* __restrict__ bias,
    void* __restrict__ outp)
{
    __shared__ unsigned short As[128][40];   // 128 rows x 32k (+8 pad)
    __shared__ unsigned short Ws[128][40];   // 128 n    x 32k (+8 pad)

    int tid = threadIdx.x;
    int w = tid >> 6;
    int l = tid & 63;
    int row0 = blockIdx.x * 128;

    f32x4 acc[2][8];
#pragma unroll
    for (int h = 0; h < 2; ++h)
#pragma unroll
        for (int nt = 0; nt < 8; ++nt) acc[h][nt] = (f32x4){0.f, 0.f, 0.f, 0.f};

    for (int kt = 0; kt < 8; ++kt) {
        const unsigned short* Asrc = (kt < 4) ? Ab : Bb;
        const unsigned short* Wsrc = (kt < 4) ? Wlt : Wrt;
        int k0 = (kt & 3) * 32;
#pragma unroll
        for (int rep = 0; rep < 2; ++rep) {
            int idx = tid + 256 * rep;
            int rr = idx >> 2, c4 = idx & 3;
            int arow = row0 + rr; if (arow > N_NODES - 1) arow = N_NODES - 1;
            *(uint4*)&As[rr][c4 * 8] = *(const uint4*)&Asrc[arow * D + k0 + c4 * 8];
        }
#pragma unroll
        for (int rep = 0; rep < 2; ++rep) {
            int idx = tid + 256 * rep;
            int rr = idx >> 2, c4 = idx & 3;
            *(uint4*)&Ws[rr][c4 * 8] = *(const uint4*)&Wsrc[rr * D + k0 + c4 * 8];
        }
        __syncthreads();
        int kb = l >> 4, m16 = l & 15;
        short8 A0 = *(const short8*)&As[32 * w + m16][kb * 8];
        short8 A1 = *(const short8*)&As[32 * w + 16 + m16][kb * 8];
#pragma unroll
        for (int nt = 0; nt < 8; ++nt) {
            short8 b = *(const short8*)&Ws[nt * 16 + m16][kb * 8];
            acc[0][nt] = __builtin_amdgcn_mfma_f32_16x16x32_bf16(A0, b, acc[0][nt], 0, 0, 0);
            acc[1][nt] = __builtin_amdgcn_mfma_f32_16x16x32_bf16(A1, b, acc[1][nt], 0, 0, 0);
        }
        __syncthreads();
    }

    // epilogue: C[row=(l>>4)*4+i][col=l&15] per 16x16 tile (m89-verified)
    int cbase = l & 15;
#pragma unroll
    for (int h = 0; h < 2; ++h) {
        int rbase = row0 + 32 * w + 16 * h + ((l >> 4) << 2);
#pragma unroll
        for (int nt = 0; nt < 8; ++nt) {
            int col = nt * 16 + cbase;
            float bv = bias[col];
#pragma unroll
            for (int i = 0; i < 4; ++i) {
                int row = rbase + i;
                if (row < N_NODES) {
                    float v = acc[h][nt][i] + bv;
                    if (RELU) v = fmaxf(v, 0.f);
                    if (OUT_BF16) ((unsigned short*)outp)[row * D + col] = f2bf(v);
                    else          ((float*)outp)[row * D + col] = v;
                }
            }
        }
    }
}

// ---------------- launch ----------------

static inline size_t align_up(size_t v, size_t a) { return (v + a - 1) / a * a; }

extern "C" void kernel_launch(void* const* d_in, const int* in_sizes, int n_in,
                              void* d_out, int out_size, void* d_ws, size_t ws_size,
                              hipStream_t stream) {
    const float* x   = (const float*)d_in[0];
    const int*   ei  = (const int*)d_in[1];
    const int*   src = ei;
    const int*   dst = ei + N_EDGES;
    const float* Wl0 = (const float*)d_in[2];
    const float* b0  = (const float*)d_in[3];
    const float* Wr0 = (const float*)d_in[4];
    const float* Wl1 = (const float*)d_in[5];
    const float* b1  = (const float*)d_in[6];
    const float* Wr1 = (const float*)d_in[7];
    float* out = (float*)d_out;

    // workspace layout (~58.5 MB); deg8/rank/offs8 overlap aggrb (dead before
    // first k_aggr_b write).
    char* w = (char*)d_ws;
    int* deg    = (int*)w;                  w += align_up(N_NODES * 4, 256);
    int* offs   = (int*)w;                  w += align_up(N_NODES * 4, 256);
    int* bsum   = (int*)w;                  w += align_up(512 * 4, 256);
    int* csr    = (int*)w;                  w += align_up((size_t)N_EDGES * 4, 256);
    unsigned short* xb    = (unsigned short*)w;  w += align_up((size_t)N_NODES * D * 2, 256); // becomes h after layer 0
    unsigned short* Wt    = (unsigned short*)w;  w += align_up((size_t)4 * D * D * 2, 256);
    unsigned short* aggrb = (unsigned short*)w;  w += align_up((size_t)N_NODES * D * 2, 256);
    // transient region inside aggrb:
    int* deg8  = (int*)aggrb;                          // 3.2 MB
    int* rank  = deg8 + 8 * N_NODES;                   // 6.4 MB
    int* offs8 = rank + N_EDGES;                       // 3.2 MB  (total 12.8 < 25.6 MB)
    unsigned short* Wt_l0 = Wt + 0 * D * D;
    unsigned short* Wt_r0 = Wt + 1 * D * D;
    unsigned short* Wt_l1 = Wt + 2 * D * D;
    unsigned short* Wt_r1 = Wt + 3 * D * D;

    const int nScanBlocks = (N_NODES + 255) / 256;   // 391
    const int nEdgeBlocks = N_EDGES / 256;           // 6250 (exact)
    const int nPreBlocks  = 6250 + 6250 + 4;         // hist + cast_x + cast_w
    const int nAggrBlocks = N_NODES / 4;             // 25000
    const int nGemmBlocks = (N_NODES + 127) / 128;   // 782

    hipMemsetAsync(deg8, 0, (size_t)8 * N_NODES * sizeof(int), stream);
    k_pre<<<nPreBlocks, 256, 0, stream>>>(dst, deg8, rank, x, xb,
                                          Wl0, Wr0, Wl1, Wr1, Wt);
    k_scan1<<<nScanBlocks, 256, 0, stream>>>(deg8, deg, offs, bsum);
    k_scan2<<<1, 512, 0, stream>>>(bsum, nScanBlocks);
    k_offs8<<<nScanBlocks, 256, 0, stream>>>(offs, bsum, deg8, offs, offs8);
    k_place<<<nEdgeBlocks, 256, 0, stream>>>(src, dst, rank, offs8, csr);

    // layer 0: h = relu(aggr@Wl0 + x@Wr0 + b0) -> xb (in place, bf16)
    k_aggr_b<<<nAggrBlocks, 256, 0, stream>>>(xb, offs, deg, csr, aggrb);
    k_gemm_mfma<1, 1><<<nGemmBlocks, 256, 0, stream>>>(aggrb, xb, Wt_l0, Wt_r0, b0, xb);

    // layer 1: out = aggr_h@Wl1 + h@Wr1 + b1 -> d_out (fp32)
    k_aggr_b<<<nAggrBlocks, 256, 0, stream>>>(xb, offs, deg, csr, aggrb);
    k_gemm_mfma<0, 0><<<nGemmBlocks, 256, 0, stream>>>(aggrb, xb, Wt_l1, Wt_r1, b1, out);
}

// Round 11
// 410.460 us; speedup vs baseline: 1.0331x; 1.0331x over previous
//
#include <hip/hip_runtime.h>
#include <hip/hip_bf16.h>

#define N_NODES 100000
#define N_EDGES 1600000
#define D 128

typedef __attribute__((ext_vector_type(8))) short short8;
typedef __attribute__((ext_vector_type(4))) float f32x4;

__device__ __forceinline__ float bf2f(unsigned short u) {
    union { unsigned int i; float f; } c; c.i = ((unsigned int)u) << 16; return c.f;
}
__device__ __forceinline__ unsigned short f2bf(float f) {
    union { float f; unsigned int i; } c; c.f = f;
    unsigned int u = c.i;
    return (unsigned short)((u + 0x7fffu + ((u >> 16) & 1u)) >> 16);   // RNE
}

// ---------------- CSR build ----------------
// 8-way privatized histogram, atomic-return = rank. Kept SEPARATE from any
// streaming work: r9 showed the memory-side atomic stream does not overlap
// with cast traffic (fused k_pre 90us vs 65+12 split).

__global__ __launch_bounds__(256) void k_deg8(const int* __restrict__ dst,
                                              int* __restrict__ deg8,
                                              int* __restrict__ rank) {
    int e = blockIdx.x * 256 + threadIdx.x;   // grid exact: 6250*256 == N_EDGES
    int c = blockIdx.x & 7;
    rank[e] = atomicAdd(&deg8[c * N_NODES + dst[e]], 1);
}

// fused: deg = sum(deg8); block-local exclusive scan -> offsP, bsum.
// Blocks [391, 391+6250): x -> bf16 cast (streaming, no atomics -> overlaps fine).
__global__ void k_scan1(const int* __restrict__ deg8, int* __restrict__ deg,
                        int* __restrict__ offsP, int* __restrict__ bsum,
                        const float* __restrict__ x, unsigned short* __restrict__ xb) {
    __shared__ int s[256];
    int b = blockIdx.x;
    if (b >= 391) {                    // cast_x: 6250*256*8 == N_NODES*D exact
        int i = (b - 391) * 256 + threadIdx.x;
        int base = i * 8;
        float4 a = *(const float4*)&x[base];
        float4 v = *(const float4*)&x[base + 4];
        uint4 o;
        o.x = (unsigned)f2bf(a.x) | ((unsigned)f2bf(a.y) << 16);
        o.y = (unsigned)f2bf(a.z) | ((unsigned)f2bf(a.w) << 16);
        o.z = (unsigned)f2bf(v.x) | ((unsigned)f2bf(v.y) << 16);
        o.w = (unsigned)f2bf(v.z) | ((unsigned)f2bf(v.w) << 16);
        *(uint4*)&xb[base] = o;
        return;
    }
    int i = b * 256 + threadIdx.x;
    int v = 0;
    if (i < N_NODES) {
#pragma unroll
        for (int c = 0; c < 8; ++c) v += deg8[c * N_NODES + i];
        deg[i] = v;
    }
    s[threadIdx.x] = v;
    __syncthreads();
    for (int off = 1; off < 256; off <<= 1) {
        int t = (threadIdx.x >= off) ? s[threadIdx.x - off] : 0;
        __syncthreads();
        s[threadIdx.x] += t;
        __syncthreads();
    }
    if (i < N_NODES) offsP[i] = s[threadIdx.x] - v;
    if (threadIdx.x == 255) bsum[b] = s[255];
}

__global__ void k_scan2(int* __restrict__ bsum, int nb) {
    __shared__ int s[512];
    int t = threadIdx.x;
    int v = (t < nb) ? bsum[t] : 0;
    s[t] = v;
    __syncthreads();
    for (int off = 1; off < 512; off <<= 1) {
        int u = (t >= off) ? s[t - off] : 0;
        __syncthreads();
        s[t] += u;
        __syncthreads();
    }
    if (t < nb) bsum[t] = s[t] - v;
}

// offs8[c][i] = global offs + per-copy prefix. Blocks [391,395): weight casts.
__global__ __launch_bounds__(256) void k_offs8(const int* __restrict__ offsP,
                                               const int* __restrict__ bsum,
                                               const int* __restrict__ deg8,
                                               int* __restrict__ offs,
                                               int* __restrict__ offs8,
                                               const float* __restrict__ W0,
                                               const float* __restrict__ W1,
                                               const float* __restrict__ W2,
                                               const float* __restrict__ W3,
                                               unsigned short* __restrict__ T) {
    int b = blockIdx.x;
    if (b >= 391) {                    // cast_w: W[k][n] fp32 -> T[n][k] bf16
        int m = b - 391;
        const float* W = (m == 0) ? W0 : (m == 1) ? W1 : (m == 2) ? W2 : W3;
        unsigned short* Tm = T + m * D * D;
        int n = threadIdx.x & 127;
        int kh = (threadIdx.x >> 7) * 64;
        for (int k = kh; k < kh + 64; ++k)
            Tm[n * D + k] = f2bf(W[k * D + n]);
        return;
    }
    int i = b * 256 + threadIdx.x;
    if (i < N_NODES) {
        int o = offsP[i] + bsum[b];
        offs[i] = o;
#pragma unroll
        for (int c = 0; c < 8; ++c) {
            offs8[c * N_NODES + i] = o;
            o += deg8[c * N_NODES + i];
        }
    }
}

__global__ __launch_bounds__(256) void k_place(const int* __restrict__ src,
                                               const int* __restrict__ dst,
                                               const int* __restrict__ rank,
                                               const int* __restrict__ offs8,
                                               int* __restrict__ csr) {
    int e = blockIdx.x * 256 + threadIdx.x;   // same geometry as k_deg8
    int c = blockIdx.x & 7;
    int d = dst[e];
    csr[offs8[c * N_NODES + d] + rank[e]] = src[e];   // plain store (NT regressed, r9)
}

// ---------------- mean aggregation v3 ----------------
// Quarter-wave (16 lanes) per edge, uint4 (8 bf16) per lane -> one wave load
// covers 4 edges x 256B. 8 gathers in flight in the unrolled loop. Reduce
// across edge-groups via shfl_xor(16|32); lanes 0-15 store the row.

__global__ __launch_bounds__(256) void k_aggr_b(
    const unsigned short* __restrict__ xb, const int* __restrict__ offs,
    const int* __restrict__ deg, const int* __restrict__ csr,
    unsigned short* __restrict__ aggrb)
{
    int wave = threadIdx.x >> 6;
    int l = threadIdx.x & 63;
    int g = l >> 4;               // edge slot within quad
    int li = l & 15;              // feature octet: features [li*8, li*8+8)
    int node = blockIdx.x * 4 + wave;
    if (node >= N_NODES) return;
    int start = offs[node];
    int d = deg[node];
    float a0 = 0.f, a1 = 0.f, a2 = 0.f, a3 = 0.f;
    float a4 = 0.f, a5 = 0.f, a6 = 0.f, a7 = 0.f;
    int e = 0;
    for (; e + 8 <= d; e += 8) {
        int j0 = csr[start + e + g];
        int j1 = csr[start + e + 4 + g];
        uint4 v0 = *(const uint4*)&xb[j0 * D + li * 8];
        uint4 v1 = *(const uint4*)&xb[j1 * D + li * 8];
        a0 += bf2f(v0.x & 0xffff) + bf2f(v1.x & 0xffff);
        a1 += bf2f(v0.x >> 16)    + bf2f(v1.x >> 16);
        a2 += bf2f(v0.y & 0xffff) + bf2f(v1.y & 0xffff);
        a3 += bf2f(v0.y >> 16)    + bf2f(v1.y >> 16);
        a4 += bf2f(v0.z & 0xffff) + bf2f(v1.z & 0xffff);
        a5 += bf2f(v0.z >> 16)    + bf2f(v1.z >> 16);
        a6 += bf2f(v0.w & 0xffff) + bf2f(v1.w & 0xffff);
        a7 += bf2f(v0.w >> 16)    + bf2f(v1.w >> 16);
    }
    if (e + 4 <= d) {
        int j = csr[start + e + g];
        uint4 v = *(const uint4*)&xb[j * D + li * 8];
        a0 += bf2f(v.x & 0xffff); a1 += bf2f(v.x >> 16);
        a2 += bf2f(v.y & 0xffff); a3 += bf2f(v.y >> 16);
        a4 += bf2f(v.z & 0xffff); a5 += bf2f(v.z >> 16);
        a6 += bf2f(v.w & 0xffff); a7 += bf2f(v.w >> 16);
        e += 4;
    }
    if (e + g < d) {              // tail 1..3 edges, group-guarded
        int j = csr[start + e + g];
        uint4 v = *(const uint4*)&xb[j * D + li * 8];
        a0 += bf2f(v.x & 0xffff); a1 += bf2f(v.x >> 16);
        a2 += bf2f(v.y & 0xffff); a3 += bf2f(v.y >> 16);
        a4 += bf2f(v.z & 0xffff); a5 += bf2f(v.z >> 16);
        a6 += bf2f(v.w & 0xffff); a7 += bf2f(v.w >> 16);
    }
    a0 += __shfl_xor(a0, 16, 64); a0 += __shfl_xor(a0, 32, 64);
    a1 += __shfl_xor(a1, 16, 64); a1 += __shfl_xor(a1, 32, 64);
    a2 += __shfl_xor(a2, 16, 64); a2 += __shfl_xor(a2, 32, 64);
    a3 += __shfl_xor(a3, 16, 64); a3 += __shfl_xor(a3, 32, 64);
    a4 += __shfl_xor(a4, 16, 64); a4 += __shfl_xor(a4, 32, 64);
    a5 += __shfl_xor(a5, 16, 64); a5 += __shfl_xor(a5, 32, 64);
    a6 += __shfl_xor(a6, 16, 64); a6 += __shfl_xor(a6, 32, 64);
    a7 += __shfl_xor(a7, 16, 64); a7 += __shfl_xor(a7, 32, 64);
    if (g == 0) {
        float inv = 1.f / (float)(d > 0 ? d : 1);
        uint4 o;
        o.x = (unsigned)f2bf(a0 * inv) | ((unsigned)f2bf(a1 * inv) << 16);
        o.y = (unsigned)f2bf(a2 * inv) | ((unsigned)f2bf(a3 * inv) << 16);
        o.z = (unsigned)f2bf(a4 * inv) | ((unsigned)f2bf(a5 * inv) << 16);
        o.w = (unsigned)f2bf(a6 * inv) | ((unsigned)f2bf(a7 * inv) << 16);
        *(uint4*)&aggrb[node * D + li * 8] = o;
    }
}

// ---------------- MFMA GEMM: out = A@Wl + B@Wr + bias ----------------
// BM=128 rows/block, 4 waves x 32 rows (2 A-frags reused over 8 B-frags).

template<int OUT_BF16, int RELU>
__global__ __launch_bounds__(256) void k_gemm_mfma(
    const unsigned short* __restrict__ Ab,   // aggr bf16 [N][D]
    const unsigned short* __restrict__ Bb,   // x/h  bf16 [N][D] (may alias out when OUT_BF16)
    const unsigned short* __restrict__ Wlt,  // [n][k] bf16
    const unsigned short* __restrict__ Wrt,  // [n][k] bf16
    const float* __restrict__ bias,
    void* __restrict__ outp)
{
    __shared__ unsigned short As[128][40];   // 128 rows x 32k (+8 pad)
    __shared__ unsigned short Ws[128][40];   // 128 n    x 32k (+8 pad)

    int tid = threadIdx.x;
    int w = tid >> 6;
    int l = tid & 63;
    int row0 = blockIdx.x * 128;

    f32x4 acc[2][8];
#pragma unroll
    for (int h = 0; h < 2; ++h)
#pragma unroll
        for (int nt = 0; nt < 8; ++nt) acc[h][nt] = (f32x4){0.f, 0.f, 0.f, 0.f};

    for (int kt = 0; kt < 8; ++kt) {
        const unsigned short* Asrc = (kt < 4) ? Ab : Bb;
        const unsigned short* Wsrc = (kt < 4) ? Wlt : Wrt;
        int k0 = (kt & 3) * 32;
#pragma unroll
        for (int rep = 0; rep < 2; ++rep) {
            int idx = tid + 256 * rep;
            int rr = idx >> 2, c4 = idx & 3;
            int arow = row0 + rr; if (arow > N_NODES - 1) arow = N_NODES - 1;
            *(uint4*)&As[rr][c4 * 8] = *(const uint4*)&Asrc[arow * D + k0 + c4 * 8];
        }
#pragma unroll
        for (int rep = 0; rep < 2; ++rep) {
            int idx = tid + 256 * rep;
            int rr = idx >> 2, c4 = idx & 3;
            *(uint4*)&Ws[rr][c4 * 8] = *(const uint4*)&Wsrc[rr * D + k0 + c4 * 8];
        }
        __syncthreads();
        int kb = l >> 4, m16 = l & 15;
        short8 A0 = *(const short8*)&As[32 * w + m16][kb * 8];
        short8 A1 = *(const short8*)&As[32 * w + 16 + m16][kb * 8];
#pragma unroll
        for (int nt = 0; nt < 8; ++nt) {
            short8 b = *(const short8*)&Ws[nt * 16 + m16][kb * 8];
            acc[0][nt] = __builtin_amdgcn_mfma_f32_16x16x32_bf16(A0, b, acc[0][nt], 0, 0, 0);
            acc[1][nt] = __builtin_amdgcn_mfma_f32_16x16x32_bf16(A1, b, acc[1][nt], 0, 0, 0);
        }
        __syncthreads();
    }

    // epilogue: C[row=(l>>4)*4+i][col=l&15] per 16x16 tile (m89-verified)
    int cbase = l & 15;
#pragma unroll
    for (int h = 0; h < 2; ++h) {
        int rbase = row0 + 32 * w + 16 * h + ((l >> 4) << 2);
#pragma unroll
        for (int nt = 0; nt < 8; ++nt) {
            int col = nt * 16 + cbase;
            float bv = bias[col];
#pragma unroll
            for (int i = 0; i < 4; ++i) {
                int row = rbase + i;
                if (row < N_NODES) {
                    float v = acc[h][nt][i] + bv;
                    if (RELU) v = fmaxf(v, 0.f);
                    if (OUT_BF16) ((unsigned short*)outp)[row * D + col] = f2bf(v);
                    else          ((float*)outp)[row * D + col] = v;
                }
            }
        }
    }
}

// ---------------- launch ----------------

static inline size_t align_up(size_t v, size_t a) { return (v + a - 1) / a * a; }

extern "C" void kernel_launch(void* const* d_in, const int* in_sizes, int n_in,
                              void* d_out, int out_size, void* d_ws, size_t ws_size,
                              hipStream_t stream) {
    const float* x   = (const float*)d_in[0];
    const int*   ei  = (const int*)d_in[1];
    const int*   src = ei;
    const int*   dst = ei + N_EDGES;
    const float* Wl0 = (const float*)d_in[2];
    const float* b0  = (const float*)d_in[3];
    const float* Wr0 = (const float*)d_in[4];
    const float* Wl1 = (const float*)d_in[5];
    const float* b1  = (const float*)d_in[6];
    const float* Wr1 = (const float*)d_in[7];
    float* out = (float*)d_out;

    // workspace layout (~58.5 MB); deg8/rank/offs8 overlap aggrb (dead before
    // first k_aggr_b write).
    char* w = (char*)d_ws;
    int* deg    = (int*)w;                  w += align_up(N_NODES * 4, 256);
    int* offs   = (int*)w;                  w += align_up(N_NODES * 4, 256);
    int* bsum   = (int*)w;                  w += align_up(512 * 4, 256);
    int* csr    = (int*)w;                  w += align_up((size_t)N_EDGES * 4, 256);
    unsigned short* xb    = (unsigned short*)w;  w += align_up((size_t)N_NODES * D * 2, 256); // becomes h after layer 0
    unsigned short* Wt    = (unsigned short*)w;  w += align_up((size_t)4 * D * D * 2, 256);
    unsigned short* aggrb = (unsigned short*)w;  w += align_up((size_t)N_NODES * D * 2, 256);
    // transient region inside aggrb:
    int* deg8  = (int*)aggrb;                          // 3.2 MB
    int* rank  = deg8 + 8 * N_NODES;                   // 6.4 MB
    int* offs8 = rank + N_EDGES;                       // 3.2 MB  (total 12.8 < 25.6 MB)
    unsigned short* Wt_l0 = Wt + 0 * D * D;
    unsigned short* Wt_r0 = Wt + 1 * D * D;
    unsigned short* Wt_l1 = Wt + 2 * D * D;
    unsigned short* Wt_r1 = Wt + 3 * D * D;

    const int nScanBlocks = (N_NODES + 255) / 256;   // 391
    const int nEdgeBlocks = N_EDGES / 256;           // 6250 (exact)
    const int nAggrBlocks = N_NODES / 4;             // 25000
    const int nGemmBlocks = (N_NODES + 127) / 128;   // 782

    hipMemsetAsync(deg8, 0, (size_t)8 * N_NODES * sizeof(int), stream);
    k_deg8<<<nEdgeBlocks, 256, 0, stream>>>(dst, deg8, rank);
    k_scan1<<<nScanBlocks + 6250, 256, 0, stream>>>(deg8, deg, offs, bsum, x, xb);
    k_scan2<<<1, 512, 0, stream>>>(bsum, nScanBlocks);
    k_offs8<<<nScanBlocks + 4, 256, 0, stream>>>(offs, bsum, deg8, offs, offs8,
                                                 Wl0, Wr0, Wl1, Wr1, Wt);
    k_place<<<nEdgeBlocks, 256, 0, stream>>>(src, dst, rank, offs8, csr);

    // layer 0: h = relu(aggr@Wl0 + x@Wr0 + b0) -> xb (in place, bf16)
    k_aggr_b<<<nAggrBlocks, 256, 0, stream>>>(xb, offs, deg, csr, aggrb);
    k_gemm_mfma<1, 1><<<nGemmBlocks, 256, 0, stream>>>(aggrb, xb, Wt_l0, Wt_r0, b0, xb);

    // layer 1: out = aggr_h@Wl1 + h@Wr1 + b1 -> d_out (fp32)
    k_aggr_b<<<nAggrBlocks, 256, 0, stream>>>(xb, offs, deg, csr, aggrb);
    k_gemm_mfma<0, 0><<<nGemmBlocks, 256, 0, stream>>>(aggrb, xb, Wt_l1, Wt_r1, b1, out);
}

// Round 14
// 410.284 us; speedup vs baseline: 1.0336x; 1.0004x over previous
//
#include <hip/hip_runtime.h>
#include <hip/hip_bf16.h>

#define N_NODES 100000
#define N_EDGES 1600000
#define D 128

typedef __attribute__((ext_vector_type(8))) short short8;
typedef __attribute__((ext_vector_type(4))) float f32x4;

__device__ __forceinline__ float bf2f(unsigned short u) {
    union { unsigned int i; float f; } c; c.i = ((unsigned int)u) << 16; return c.f;
}
__device__ __forceinline__ unsigned short f2bf(float f) {
    union { float f; unsigned int i; } c; c.f = f;
    unsigned int u = c.i;
    return (unsigned short)((u + 0x7fffu + ((u >> 16) & 1u)) >> 16);   // RNE
}

// ---------------- CSR build ----------------
// 8-way privatized histogram, atomic-return = rank. Kept SEPARATE from any
// streaming work: r9 showed the memory-side atomic stream does not overlap
// with cast traffic (fused k_pre 90us vs 65+12 split).

__global__ __launch_bounds__(256) void k_deg8(const int* __restrict__ dst,
                                              int* __restrict__ deg8,
                                              int* __restrict__ rank) {
    int e = blockIdx.x * 256 + threadIdx.x;   // grid exact: 6250*256 == N_EDGES
    int c = blockIdx.x & 7;
    rank[e] = atomicAdd(&deg8[c * N_NODES + dst[e]], 1);
}

// fused: deg = sum(deg8); block-local exclusive scan -> offsP, bsum (raw totals).
// Blocks [391, 391+6250): x -> bf16 cast (streaming, no atomics -> overlaps fine).
__global__ void k_scan1(const int* __restrict__ deg8, int* __restrict__ deg,
                        int* __restrict__ offsP, int* __restrict__ bsum,
                        const float* __restrict__ x, unsigned short* __restrict__ xb) {
    __shared__ int s[256];
    int b = blockIdx.x;
    if (b >= 391) {                    // cast_x: 6250*256*8 == N_NODES*D exact
        int i = (b - 391) * 256 + threadIdx.x;
        int base = i * 8;
        float4 a = *(const float4*)&x[base];
        float4 v = *(const float4*)&x[base + 4];
        uint4 o;
        o.x = (unsigned)f2bf(a.x) | ((unsigned)f2bf(a.y) << 16);
        o.y = (unsigned)f2bf(a.z) | ((unsigned)f2bf(a.w) << 16);
        o.z = (unsigned)f2bf(v.x) | ((unsigned)f2bf(v.y) << 16);
        o.w = (unsigned)f2bf(v.z) | ((unsigned)f2bf(v.w) << 16);
        *(uint4*)&xb[base] = o;
        return;
    }
    int i = b * 256 + threadIdx.x;
    int v = 0;
    if (i < N_NODES) {
#pragma unroll
        for (int c = 0; c < 8; ++c) v += deg8[c * N_NODES + i];
        deg[i] = v;
    }
    s[threadIdx.x] = v;
    __syncthreads();
    for (int off = 1; off < 256; off <<= 1) {
        int t = (threadIdx.x >= off) ? s[threadIdx.x - off] : 0;
        __syncthreads();
        s[threadIdx.x] += t;
        __syncthreads();
    }
    if (i < N_NODES) offsP[i] = s[threadIdx.x] - v;
    if (threadIdx.x == 255) bsum[b] = s[255];   // raw block total (no scan2 pass)
}

// offs8[c][i] = global offs + per-copy prefix. Inlines the bsum prefix as a
// per-block REDUCTION (S_b = sum_{j<b} bsum[j]) -- k_scan2 eliminated.
// Blocks [391,395): weight casts.
__global__ __launch_bounds__(256) void k_offs8(const int* __restrict__ offsP,
                                               const int* __restrict__ bsum,
                                               const int* __restrict__ deg8,
                                               int* __restrict__ offs,
                                               int* __restrict__ offs8,
                                               const float* __restrict__ W0,
                                               const float* __restrict__ W1,
                                               const float* __restrict__ W2,
                                               const float* __restrict__ W3,
                                               unsigned short* __restrict__ T) {
    int b = blockIdx.x;
    if (b >= 391) {                    // cast_w: W[k][n] fp32 -> T[n][k] bf16
        int m = b - 391;
        const float* W = (m == 0) ? W0 : (m == 1) ? W1 : (m == 2) ? W2 : W3;
        unsigned short* Tm = T + m * D * D;
        int n = threadIdx.x & 127;
        int kh = (threadIdx.x >> 7) * 64;
        for (int k = kh; k < kh + 64; ++k)
            Tm[n * D + k] = f2bf(W[k * D + n]);
        return;
    }
    // inline exclusive prefix of bsum for this block: reduction over [0, b)
    __shared__ int wsum[4];
    int partial = 0;
    for (int t = threadIdx.x; t < b; t += 256) partial += bsum[t];
#pragma unroll
    for (int off = 32; off > 0; off >>= 1) partial += __shfl_down(partial, off, 64);
    if ((threadIdx.x & 63) == 0) wsum[threadIdx.x >> 6] = partial;
    __syncthreads();
    int S = wsum[0] + wsum[1] + wsum[2] + wsum[3];

    int i = b * 256 + threadIdx.x;
    if (i < N_NODES) {
        int o = offsP[i] + S;
        offs[i] = o;
#pragma unroll
        for (int c = 0; c < 8; ++c) {
            offs8[c * N_NODES + i] = o;
            o += deg8[c * N_NODES + i];
        }
    }
}

__global__ __launch_bounds__(256) void k_place(const int* __restrict__ src,
                                               const int* __restrict__ rank,
                                               const int* __restrict__ dst,
                                               const int* __restrict__ offs8,
                                               int* __restrict__ csr) {
    int e = blockIdx.x * 256 + threadIdx.x;   // same geometry as k_deg8
    int c = blockIdx.x & 7;
    // src/dst/rank are single-use streams: NT loads keep them out of L2 so the
    // reused random-read offs8 table (3.2 MB) stays cached. (NT *store* on csr
    // regressed in r9 -- loads are a different mechanism, write path untouched.)
    int d = __builtin_nontemporal_load(&dst[e]);
    int r = __builtin_nontemporal_load(&rank[e]);
    int s = __builtin_nontemporal_load(&src[e]);
    csr[offs8[c * N_NODES + d] + r] = s;
}

// ---------------- mean aggregation v3 ----------------
// Quarter-wave (16 lanes) per edge, uint4 (8 bf16) per lane -> one wave load
// covers 4 edges x 256B. csr stream via NT loads (single-use; keep L2 for xb).

__global__ __launch_bounds__(256) void k_aggr_b(
    const unsigned short* __restrict__ xb, const int* __restrict__ offs,
    const int* __restrict__ deg, const int* __restrict__ csr,
    unsigned short* __restrict__ aggrb)
{
    int wave = threadIdx.x >> 6;
    int l = threadIdx.x & 63;
    int g = l >> 4;               // edge slot within quad
    int li = l & 15;              // feature octet: features [li*8, li*8+8)
    int node = blockIdx.x * 4 + wave;
    if (node >= N_NODES) return;
    int start = offs[node];
    int d = deg[node];
    float a0 = 0.f, a1 = 0.f, a2 = 0.f, a3 = 0.f;
    float a4 = 0.f, a5 = 0.f, a6 = 0.f, a7 = 0.f;
    int e = 0;
    for (; e + 8 <= d; e += 8) {
        int j0 = __builtin_nontemporal_load(&csr[start + e + g]);
        int j1 = __builtin_nontemporal_load(&csr[start + e + 4 + g]);
        uint4 v0 = *(const uint4*)&xb[j0 * D + li * 8];
        uint4 v1 = *(const uint4*)&xb[j1 * D + li * 8];
        a0 += bf2f(v0.x & 0xffff) + bf2f(v1.x & 0xffff);
        a1 += bf2f(v0.x >> 16)    + bf2f(v1.x >> 16);
        a2 += bf2f(v0.y & 0xffff) + bf2f(v1.y & 0xffff);
        a3 += bf2f(v0.y >> 16)    + bf2f(v1.y >> 16);
        a4 += bf2f(v0.z & 0xffff) + bf2f(v1.z & 0xffff);
        a5 += bf2f(v0.z >> 16)    + bf2f(v1.z >> 16);
        a6 += bf2f(v0.w & 0xffff) + bf2f(v1.w & 0xffff);
        a7 += bf2f(v0.w >> 16)    + bf2f(v1.w >> 16);
    }
    if (e + 4 <= d) {
        int j = __builtin_nontemporal_load(&csr[start + e + g]);
        uint4 v = *(const uint4*)&xb[j * D + li * 8];
        a0 += bf2f(v.x & 0xffff); a1 += bf2f(v.x >> 16);
        a2 += bf2f(v.y & 0xffff); a3 += bf2f(v.y >> 16);
        a4 += bf2f(v.z & 0xffff); a5 += bf2f(v.z >> 16);
        a6 += bf2f(v.w & 0xffff); a7 += bf2f(v.w >> 16);
        e += 4;
    }
    if (e + g < d) {              // tail 1..3 edges, group-guarded
        int j = __builtin_nontemporal_load(&csr[start + e + g]);
        uint4 v = *(const uint4*)&xb[j * D + li * 8];
        a0 += bf2f(v.x & 0xffff); a1 += bf2f(v.x >> 16);
        a2 += bf2f(v.y & 0xffff); a3 += bf2f(v.y >> 16);
        a4 += bf2f(v.z & 0xffff); a5 += bf2f(v.z >> 16);
        a6 += bf2f(v.w & 0xffff); a7 += bf2f(v.w >> 16);
    }
    a0 += __shfl_xor(a0, 16, 64); a0 += __shfl_xor(a0, 32, 64);
    a1 += __shfl_xor(a1, 16, 64); a1 += __shfl_xor(a1, 32, 64);
    a2 += __shfl_xor(a2, 16, 64); a2 += __shfl_xor(a2, 32, 64);
    a3 += __shfl_xor(a3, 16, 64); a3 += __shfl_xor(a3, 32, 64);
    a4 += __shfl_xor(a4, 16, 64); a4 += __shfl_xor(a4, 32, 64);
    a5 += __shfl_xor(a5, 16, 64); a5 += __shfl_xor(a5, 32, 64);
    a6 += __shfl_xor(a6, 16, 64); a6 += __shfl_xor(a6, 32, 64);
    a7 += __shfl_xor(a7, 16, 64); a7 += __shfl_xor(a7, 32, 64);
    if (g == 0) {
        float inv = 1.f / (float)(d > 0 ? d : 1);
        uint4 o;
        o.x = (unsigned)f2bf(a0 * inv) | ((unsigned)f2bf(a1 * inv) << 16);
        o.y = (unsigned)f2bf(a2 * inv) | ((unsigned)f2bf(a3 * inv) << 16);
        o.z = (unsigned)f2bf(a4 * inv) | ((unsigned)f2bf(a5 * inv) << 16);
        o.w = (unsigned)f2bf(a6 * inv) | ((unsigned)f2bf(a7 * inv) << 16);
        *(uint4*)&aggrb[node * D + li * 8] = o;
    }
}

// ---------------- MFMA GEMM: out = A@Wl + B@Wr + bias ----------------
// BM=128 rows/block, 4 waves x 32 rows (2 A-frags reused over 8 B-frags).

template<int OUT_BF16, int RELU>
__global__ __launch_bounds__(256) void k_gemm_mfma(
    const unsigned short* __restrict__ Ab,   // aggr bf16 [N][D]
    const unsigned short* __restrict__ Bb,   // x/h  bf16 [N][D] (may alias out when OUT_BF16)
    const unsigned short* __restrict__ Wlt,  // [n][k] bf16
    const unsigned short* __restrict__ Wrt,  // [n][k] bf16
    const float* __restrict__ bias,
    void* __restrict__ outp)
{
    __shared__ unsigned short As[128][40];   // 128 rows x 32k (+8 pad)
    __shared__ unsigned short Ws[128][40];   // 128 n    x 32k (+8 pad)

    int tid = threadIdx.x;
    int w = tid >> 6;
    int l = tid & 63;
    int row0 = blockIdx.x * 128;

    f32x4 acc[2][8];
#pragma unroll
    for (int h = 0; h < 2; ++h)
#pragma unroll
        for (int nt = 0; nt < 8; ++nt) acc[h][nt] = (f32x4){0.f, 0.f, 0.f, 0.f};

    for (int kt = 0; kt < 8; ++kt) {
        const unsigned short* Asrc = (kt < 4) ? Ab : Bb;
        const unsigned short* Wsrc = (kt < 4) ? Wlt : Wrt;
        int k0 = (kt & 3) * 32;
#pragma unroll
        for (int rep = 0; rep < 2; ++rep) {
            int idx = tid + 256 * rep;
            int rr = idx >> 2, c4 = idx & 3;
            int arow = row0 + rr; if (arow > N_NODES - 1) arow = N_NODES - 1;
            *(uint4*)&As[rr][c4 * 8] = *(const uint4*)&Asrc[arow * D + k0 + c4 * 8];
        }
#pragma unroll
        for (int rep = 0; rep < 2; ++rep) {
            int idx = tid + 256 * rep;
            int rr = idx >> 2, c4 = idx & 3;
            *(uint4*)&Ws[rr][c4 * 8] = *(const uint4*)&Wsrc[rr * D + k0 + c4 * 8];
        }
        __syncthreads();
        int kb = l >> 4, m16 = l & 15;
        short8 A0 = *(const short8*)&As[32 * w + m16][kb * 8];
        short8 A1 = *(const short8*)&As[32 * w + 16 + m16][kb * 8];
#pragma unroll
        for (int nt = 0; nt < 8; ++nt) {
            short8 b = *(const short8*)&Ws[nt * 16 + m16][kb * 8];
            acc[0][nt] = __builtin_amdgcn_mfma_f32_16x16x32_bf16(A0, b, acc[0][nt], 0, 0, 0);
            acc[1][nt] = __builtin_amdgcn_mfma_f32_16x16x32_bf16(A1, b, acc[1][nt], 0, 0, 0);
        }
        __syncthreads();
    }

    // epilogue: C[row=(l>>4)*4+i][col=l&15] per 16x16 tile (m89-verified)
    int cbase = l & 15;
#pragma unroll
    for (int h = 0; h < 2; ++h) {
        int rbase = row0 + 32 * w + 16 * h + ((l >> 4) << 2);
#pragma unroll
        for (int nt = 0; nt < 8; ++nt) {
            int col = nt * 16 + cbase;
            float bv = bias[col];
#pragma unroll
            for (int i = 0; i < 4; ++i) {
                int row = rbase + i;
                if (row < N_NODES) {
                    float v = acc[h][nt][i] + bv;
                    if (RELU) v = fmaxf(v, 0.f);
                    if (OUT_BF16) ((unsigned short*)outp)[row * D + col] = f2bf(v);
                    else          ((float*)outp)[row * D + col] = v;
                }
            }
        }
    }
}

// ---------------- launch ----------------

static inline size_t align_up(size_t v, size_t a) { return (v + a - 1) / a * a; }

extern "C" void kernel_launch(void* const* d_in, const int* in_sizes, int n_in,
                              void* d_out, int out_size, void* d_ws, size_t ws_size,
                              hipStream_t stream) {
    const float* x   = (const float*)d_in[0];
    const int*   ei  = (const int*)d_in[1];
    const int*   src = ei;
    const int*   dst = ei + N_EDGES;
    const float* Wl0 = (const float*)d_in[2];
    const float* b0  = (const float*)d_in[3];
    const float* Wr0 = (const float*)d_in[4];
    const float* Wl1 = (const float*)d_in[5];
    const float* b1  = (const float*)d_in[6];
    const float* Wr1 = (const float*)d_in[7];
    float* out = (float*)d_out;

    // workspace layout (~58.5 MB); deg8/rank/offs8 overlap aggrb (dead before
    // first k_aggr_b write).
    char* w = (char*)d_ws;
    int* deg    = (int*)w;                  w += align_up(N_NODES * 4, 256);
    int* offs   = (int*)w;                  w += align_up(N_NODES * 4, 256);
    int* bsum   = (int*)w;                  w += align_up(512 * 4, 256);
    int* csr    = (int*)w;                  w += align_up((size_t)N_EDGES * 4, 256);
    unsigned short* xb    = (unsigned short*)w;  w += align_up((size_t)N_NODES * D * 2, 256); // becomes h after layer 0
    unsigned short* Wt    = (unsigned short*)w;  w += align_up((size_t)4 * D * D * 2, 256);
    unsigned short* aggrb = (unsigned short*)w;  w += align_up((size_t)N_NODES * D * 2, 256);
    // transient region inside aggrb:
    int* deg8  = (int*)aggrb;                          // 3.2 MB
    int* rank  = deg8 + 8 * N_NODES;                   // 6.4 MB
    int* offs8 = rank + N_EDGES;                       // 3.2 MB  (total 12.8 < 25.6 MB)
    unsigned short* Wt_l0 = Wt + 0 * D * D;
    unsigned short* Wt_r0 = Wt + 1 * D * D;
    unsigned short* Wt_l1 = Wt + 2 * D * D;
    unsigned short* Wt_r1 = Wt + 3 * D * D;

    const int nScanBlocks = (N_NODES + 255) / 256;   // 391
    const int nEdgeBlocks = N_EDGES / 256;           // 6250 (exact)
    const int nAggrBlocks = N_NODES / 4;             // 25000
    const int nGemmBlocks = (N_NODES + 127) / 128;   // 782

    hipMemsetAsync(deg8, 0, (size_t)8 * N_NODES * sizeof(int), stream);
    k_deg8<<<nEdgeBlocks, 256, 0, stream>>>(dst, deg8, rank);
    k_scan1<<<nScanBlocks + 6250, 256, 0, stream>>>(deg8, deg, offs, bsum, x, xb);
    k_offs8<<<nScanBlocks + 4, 256, 0, stream>>>(offs, bsum, deg8, offs, offs8,
                                                 Wl0, Wr0, Wl1, Wr1, Wt);
    k_place<<<nEdgeBlocks, 256, 0, stream>>>(src, rank, dst, offs8, csr);

    // layer 0: h = relu(aggr@Wl0 + x@Wr0 + b0) -> xb (in place, bf16)
    k_aggr_b<<<nAggrBlocks, 256, 0, stream>>>(xb, offs, deg, csr, aggrb);
    k_gemm_mfma<1, 1><<<nGemmBlocks, 256, 0, stream>>>(aggrb, xb, Wt_l0, Wt_r0, b0, xb);

    // layer 1: out = aggr_h@Wl1 + h@Wr1 + b1 -> d_out (fp32)
    k_aggr_b<<<nAggrBlocks, 256, 0, stream>>>(xb, offs, deg, csr, aggrb);
    k_gemm_mfma<0, 0><<<nGemmBlocks, 256, 0, stream>>>(aggrb, xb, Wt_l1, Wt_r1, b1, out);
}

// Round 15
// 400.015 us; speedup vs baseline: 1.0601x; 1.0257x over previous
//
#include <hip/hip_runtime.h>
#include <hip/hip_bf16.h>

#define N_NODES 100000
#define N_EDGES 1600000
#define D 128

typedef __attribute__((ext_vector_type(8))) short short8;
typedef __attribute__((ext_vector_type(4))) float f32x4;

// global->LDS direct copy, 16B per lane; LDS dest is wave-uniform base + lane*16
#define GLD16(g, l) __builtin_amdgcn_global_load_lds( \
    (const __attribute__((address_space(1))) void*)(g), \
    (__attribute__((address_space(3))) void*)(l), 16, 0, 0)

__device__ __forceinline__ float bf2f(unsigned short u) {
    union { unsigned int i; float f; } c; c.i = ((unsigned int)u) << 16; return c.f;
}
__device__ __forceinline__ unsigned short f2bf(float f) {
    union { float f; unsigned int i; } c; c.f = f;
    unsigned int u = c.i;
    return (unsigned short)((u + 0x7fffu + ((u >> 16) & 1u)) >> 16);   // RNE
}

// ---------------- CSR build ----------------
// 8-way privatized histogram, atomic-return = rank. Kept SEPARATE from any
// streaming work (r9: atomic stream does not overlap with cast traffic).

__global__ __launch_bounds__(256) void k_deg8(const int* __restrict__ dst,
                                              int* __restrict__ deg8,
                                              int* __restrict__ rank) {
    int e = blockIdx.x * 256 + threadIdx.x;   // grid exact: 6250*256 == N_EDGES
    int c = blockIdx.x & 7;
    rank[e] = atomicAdd(&deg8[c * N_NODES + dst[e]], 1);
}

// fused: deg = sum(deg8); block-local exclusive scan -> offsP, bsum (raw totals).
// Blocks [391, 391+6250): x -> bf16 cast.
__global__ void k_scan1(const int* __restrict__ deg8, int* __restrict__ deg,
                        int* __restrict__ offsP, int* __restrict__ bsum,
                        const float* __restrict__ x, unsigned short* __restrict__ xb) {
    __shared__ int s[256];
    int b = blockIdx.x;
    if (b >= 391) {                    // cast_x: 6250*256*8 == N_NODES*D exact
        int i = (b - 391) * 256 + threadIdx.x;
        int base = i * 8;
        float4 a = *(const float4*)&x[base];
        float4 v = *(const float4*)&x[base + 4];
        uint4 o;
        o.x = (unsigned)f2bf(a.x) | ((unsigned)f2bf(a.y) << 16);
        o.y = (unsigned)f2bf(a.z) | ((unsigned)f2bf(a.w) << 16);
        o.z = (unsigned)f2bf(v.x) | ((unsigned)f2bf(v.y) << 16);
        o.w = (unsigned)f2bf(v.z) | ((unsigned)f2bf(v.w) << 16);
        *(uint4*)&xb[base] = o;
        return;
    }
    int i = b * 256 + threadIdx.x;
    int v = 0;
    if (i < N_NODES) {
#pragma unroll
        for (int c = 0; c < 8; ++c) v += deg8[c * N_NODES + i];
        deg[i] = v;
    }
    s[threadIdx.x] = v;
    __syncthreads();
    for (int off = 1; off < 256; off <<= 1) {
        int t = (threadIdx.x >= off) ? s[threadIdx.x - off] : 0;
        __syncthreads();
        s[threadIdx.x] += t;
        __syncthreads();
    }
    if (i < N_NODES) offsP[i] = s[threadIdx.x] - v;
    if (threadIdx.x == 255) bsum[b] = s[255];
}

// offs8[c][i] = global offs + per-copy prefix; bsum prefix inlined as reduction.
// Blocks [391,395): weight casts.
__global__ __launch_bounds__(256) void k_offs8(const int* __restrict__ offsP,
                                               const int* __restrict__ bsum,
                                               const int* __restrict__ deg8,
                                               int* __restrict__ offs,
                                               int* __restrict__ offs8,
                                               const float* __restrict__ W0,
                                               const float* __restrict__ W1,
                                               const float* __restrict__ W2,
                                               const float* __restrict__ W3,
                                               unsigned short* __restrict__ T) {
    int b = blockIdx.x;
    if (b >= 391) {                    // cast_w: W[k][n] fp32 -> T[n][k] bf16
        int m = b - 391;
        const float* W = (m == 0) ? W0 : (m == 1) ? W1 : (m == 2) ? W2 : W3;
        unsigned short* Tm = T + m * D * D;
        int n = threadIdx.x & 127;
        int kh = (threadIdx.x >> 7) * 64;
        for (int k = kh; k < kh + 64; ++k)
            Tm[n * D + k] = f2bf(W[k * D + n]);
        return;
    }
    __shared__ int wsum[4];
    int partial = 0;
    for (int t = threadIdx.x; t < b; t += 256) partial += bsum[t];
#pragma unroll
    for (int off = 32; off > 0; off >>= 1) partial += __shfl_down(partial, off, 64);
    if ((threadIdx.x & 63) == 0) wsum[threadIdx.x >> 6] = partial;
    __syncthreads();
    int S = wsum[0] + wsum[1] + wsum[2] + wsum[3];

    int i = b * 256 + threadIdx.x;
    if (i < N_NODES) {
        int o = offsP[i] + S;
        offs[i] = o;
#pragma unroll
        for (int c = 0; c < 8; ++c) {
            offs8[c * N_NODES + i] = o;
            o += deg8[c * N_NODES + i];
        }
    }
}

__global__ __launch_bounds__(256) void k_place(const int* __restrict__ src,
                                               const int* __restrict__ rank,
                                               const int* __restrict__ dst,
                                               const int* __restrict__ offs8,
                                               int* __restrict__ csr) {
    int e = blockIdx.x * 256 + threadIdx.x;   // same geometry as k_deg8
    int c = blockIdx.x & 7;
    int d = __builtin_nontemporal_load(&dst[e]);
    int r = __builtin_nontemporal_load(&rank[e]);
    int s = __builtin_nontemporal_load(&src[e]);
    csr[offs8[c * N_NODES + d] + r] = s;
}

// ---------------- mean aggregation v3 ----------------
// Quarter-wave (16 lanes) per edge, uint4 (8 bf16) per lane.

__global__ __launch_bounds__(256) void k_aggr_b(
    const unsigned short* __restrict__ xb, const int* __restrict__ offs,
    const int* __restrict__ deg, const int* __restrict__ csr,
    unsigned short* __restrict__ aggrb)
{
    int wave = threadIdx.x >> 6;
    int l = threadIdx.x & 63;
    int g = l >> 4;               // edge slot within quad
    int li = l & 15;              // feature octet: features [li*8, li*8+8)
    int node = blockIdx.x * 4 + wave;
    if (node >= N_NODES) return;
    int start = offs[node];
    int d = deg[node];
    float a0 = 0.f, a1 = 0.f, a2 = 0.f, a3 = 0.f;
    float a4 = 0.f, a5 = 0.f, a6 = 0.f, a7 = 0.f;
    int e = 0;
    for (; e + 8 <= d; e += 8) {
        int j0 = __builtin_nontemporal_load(&csr[start + e + g]);
        int j1 = __builtin_nontemporal_load(&csr[start + e + 4 + g]);
        uint4 v0 = *(const uint4*)&xb[j0 * D + li * 8];
        uint4 v1 = *(const uint4*)&xb[j1 * D + li * 8];
        a0 += bf2f(v0.x & 0xffff) + bf2f(v1.x & 0xffff);
        a1 += bf2f(v0.x >> 16)    + bf2f(v1.x >> 16);
        a2 += bf2f(v0.y & 0xffff) + bf2f(v1.y & 0xffff);
        a3 += bf2f(v0.y >> 16)    + bf2f(v1.y >> 16);
        a4 += bf2f(v0.z & 0xffff) + bf2f(v1.z & 0xffff);
        a5 += bf2f(v0.z >> 16)    + bf2f(v1.z >> 16);
        a6 += bf2f(v0.w & 0xffff) + bf2f(v1.w & 0xffff);
        a7 += bf2f(v0.w >> 16)    + bf2f(v1.w >> 16);
    }
    if (e + 4 <= d) {
        int j = __builtin_nontemporal_load(&csr[start + e + g]);
        uint4 v = *(const uint4*)&xb[j * D + li * 8];
        a0 += bf2f(v.x & 0xffff); a1 += bf2f(v.x >> 16);
        a2 += bf2f(v.y & 0xffff); a3 += bf2f(v.y >> 16);
        a4 += bf2f(v.z & 0xffff); a5 += bf2f(v.z >> 16);
        a6 += bf2f(v.w & 0xffff); a7 += bf2f(v.w >> 16);
        e += 4;
    }
    if (e + g < d) {              // tail 1..3 edges, group-guarded
        int j = __builtin_nontemporal_load(&csr[start + e + g]);
        uint4 v = *(const uint4*)&xb[j * D + li * 8];
        a0 += bf2f(v.x & 0xffff); a1 += bf2f(v.x >> 16);
        a2 += bf2f(v.y & 0xffff); a3 += bf2f(v.y >> 16);
        a4 += bf2f(v.z & 0xffff); a5 += bf2f(v.z >> 16);
        a6 += bf2f(v.w & 0xffff); a7 += bf2f(v.w >> 16);
    }
    a0 += __shfl_xor(a0, 16, 64); a0 += __shfl_xor(a0, 32, 64);
    a1 += __shfl_xor(a1, 16, 64); a1 += __shfl_xor(a1, 32, 64);
    a2 += __shfl_xor(a2, 16, 64); a2 += __shfl_xor(a2, 32, 64);
    a3 += __shfl_xor(a3, 16, 64); a3 += __shfl_xor(a3, 32, 64);
    a4 += __shfl_xor(a4, 16, 64); a4 += __shfl_xor(a4, 32, 64);
    a5 += __shfl_xor(a5, 16, 64); a5 += __shfl_xor(a5, 32, 64);
    a6 += __shfl_xor(a6, 16, 64); a6 += __shfl_xor(a6, 32, 64);
    a7 += __shfl_xor(a7, 16, 64); a7 += __shfl_xor(a7, 32, 64);
    if (g == 0) {
        float inv = 1.f / (float)(d > 0 ? d : 1);
        uint4 o;
        o.x = (unsigned)f2bf(a0 * inv) | ((unsigned)f2bf(a1 * inv) << 16);
        o.y = (unsigned)f2bf(a2 * inv) | ((unsigned)f2bf(a3 * inv) << 16);
        o.z = (unsigned)f2bf(a4 * inv) | ((unsigned)f2bf(a5 * inv) << 16);
        o.w = (unsigned)f2bf(a6 * inv) | ((unsigned)f2bf(a7 * inv) << 16);
        *(uint4*)&aggrb[node * D + li * 8] = o;
    }
}

// ---------------- MFMA GEMM: out = A@Wl + B@Wr + bias ----------------
// BM=128, 4 waves x 32 rows. Staging via global_load_lds width=16 into LINEAR
// LDS [128][32] (G-mistake #1). Bank conflicts on ds_read_b128 fixed by XOR
// swizzle chunk' = chunk ^ ((row>>1)&3) applied on the GLOBAL source addr
// (per-lane) and the READ addr -- LDS dest stays linear (rule #21, m104/m173).
// Content: LDS[row][c'] = A[row][c'^s]; read kb fetches c'=kb^s -> A[row][kb].

template<int OUT_BF16, int RELU>
__global__ __launch_bounds__(256) void k_gemm_mfma(
    const unsigned short* __restrict__ Ab,   // aggr bf16 [N][D]
    const unsigned short* __restrict__ Bb,   // x/h  bf16 [N][D] (may alias out when OUT_BF16)
    const unsigned short* __restrict__ Wlt,  // [n][k] bf16
    const unsigned short* __restrict__ Wrt,  // [n][k] bf16
    const float* __restrict__ bias,
    void* __restrict__ outp)
{
    __shared__ unsigned short As[128 * 32];  // linear: row-major 128 x 32 (64B rows)
    __shared__ unsigned short Ws[128 * 32];

    int tid = threadIdx.x;
    int wv = tid >> 6;
    int l = tid & 63;
    int row0 = blockIdx.x * 128;

    f32x4 acc[2][8];
#pragma unroll
    for (int h = 0; h < 2; ++h)
#pragma unroll
        for (int nt = 0; nt < 8; ++nt) acc[h][nt] = (f32x4){0.f, 0.f, 0.f, 0.f};

    for (int kt = 0; kt < 8; ++kt) {
        const unsigned short* Asrc = (kt < 4) ? Ab : Bb;
        const unsigned short* Wsrc = (kt < 4) ? Wlt : Wrt;
        int k0 = (kt & 3) * 32;
        // stage A tile (128 rows x 32 k): 512 16B-chunks, 8 wave-issues
#pragma unroll
        for (int rep = 0; rep < 2; ++rep) {
            int base_slot = wv * 64 + rep * 256;   // wave-uniform
            int slot = base_slot + l;
            int row = slot >> 2, c = slot & 3;
            int arow = row0 + row; if (arow > N_NODES - 1) arow = N_NODES - 1;
            int gc = c ^ ((row >> 1) & 3);
            GLD16(&Asrc[arow * D + k0 + gc * 8], &As[base_slot * 8]);
        }
        // stage W tile (128 n x 32 k)
#pragma unroll
        for (int rep = 0; rep < 2; ++rep) {
            int base_slot = wv * 64 + rep * 256;   // wave-uniform
            int slot = base_slot + l;
            int row = slot >> 2, c = slot & 3;
            int gc = c ^ ((row >> 1) & 3);
            GLD16(&Wsrc[row * D + k0 + gc * 8], &Ws[base_slot * 8]);
        }
        __syncthreads();                            // compiler drains vmcnt here
        int kb = l >> 4, m16 = l & 15;
        int ra0 = 32 * wv + m16;
        int ra1 = ra0 + 16;
        short8 A0 = *(const short8*)&As[ra0 * 32 + (kb ^ ((ra0 >> 1) & 3)) * 8];
        short8 A1 = *(const short8*)&As[ra1 * 32 + (kb ^ ((ra1 >> 1) & 3)) * 8];
#pragma unroll
        for (int nt = 0; nt < 8; ++nt) {
            int rb = nt * 16 + m16;
            short8 b = *(const short8*)&Ws[rb * 32 + (kb ^ ((rb >> 1) & 3)) * 8];
            acc[0][nt] = __builtin_amdgcn_mfma_f32_16x16x32_bf16(A0, b, acc[0][nt], 0, 0, 0);
            acc[1][nt] = __builtin_amdgcn_mfma_f32_16x16x32_bf16(A1, b, acc[1][nt], 0, 0, 0);
        }
        __syncthreads();
    }

    // epilogue: C[row=(l>>4)*4+i][col=l&15] per 16x16 tile (m89-verified)
    int cbase = l & 15;
#pragma unroll
    for (int h = 0; h < 2; ++h) {
        int rbase = row0 + 32 * wv + 16 * h + ((l >> 4) << 2);
#pragma unroll
        for (int nt = 0; nt < 8; ++nt) {
            int col = nt * 16 + cbase;
            float bv = bias[col];
#pragma unroll
            for (int i = 0; i < 4; ++i) {
                int row = rbase + i;
                if (row < N_NODES) {
                    float v = acc[h][nt][i] + bv;
                    if (RELU) v = fmaxf(v, 0.f);
                    if (OUT_BF16) ((unsigned short*)outp)[row * D + col] = f2bf(v);
                    else          ((float*)outp)[row * D + col] = v;
                }
            }
        }
    }
}

// ---------------- launch ----------------

static inline size_t align_up(size_t v, size_t a) { return (v + a - 1) / a * a; }

extern "C" void kernel_launch(void* const* d_in, const int* in_sizes, int n_in,
                              void* d_out, int out_size, void* d_ws, size_t ws_size,
                              hipStream_t stream) {
    const float* x   = (const float*)d_in[0];
    const int*   ei  = (const int*)d_in[1];
    const int*   src = ei;
    const int*   dst = ei + N_EDGES;
    const float* Wl0 = (const float*)d_in[2];
    const float* b0  = (const float*)d_in[3];
    const float* Wr0 = (const float*)d_in[4];
    const float* Wl1 = (const float*)d_in[5];
    const float* b1  = (const float*)d_in[6];
    const float* Wr1 = (const float*)d_in[7];
    float* out = (float*)d_out;

    // workspace layout (~58.5 MB); deg8/rank/offs8 overlap aggrb (dead before
    // first k_aggr_b write).
    char* w = (char*)d_ws;
    int* deg    = (int*)w;                  w += align_up(N_NODES * 4, 256);
    int* offs   = (int*)w;                  w += align_up(N_NODES * 4, 256);
    int* bsum   = (int*)w;                  w += align_up(512 * 4, 256);
    int* csr    = (int*)w;                  w += align_up((size_t)N_EDGES * 4, 256);
    unsigned short* xb    = (unsigned short*)w;  w += align_up((size_t)N_NODES * D * 2, 256); // becomes h after layer 0
    unsigned short* Wt    = (unsigned short*)w;  w += align_up((size_t)4 * D * D * 2, 256);
    unsigned short* aggrb = (unsigned short*)w;  w += align_up((size_t)N_NODES * D * 2, 256);
    // transient region inside aggrb:
    int* deg8  = (int*)aggrb;                          // 3.2 MB
    int* rank  = deg8 + 8 * N_NODES;                   // 6.4 MB
    int* offs8 = rank + N_EDGES;                       // 3.2 MB  (total 12.8 < 25.6 MB)
    unsigned short* Wt_l0 = Wt + 0 * D * D;
    unsigned short* Wt_r0 = Wt + 1 * D * D;
    unsigned short* Wt_l1 = Wt + 2 * D * D;
    unsigned short* Wt_r1 = Wt + 3 * D * D;

    const int nScanBlocks = (N_NODES + 255) / 256;   // 391
    const int nEdgeBlocks = N_EDGES / 256;           // 6250 (exact)
    const int nAggrBlocks = N_NODES / 4;             // 25000
    const int nGemmBlocks = (N_NODES + 127) / 128;   // 782

    hipMemsetAsync(deg8, 0, (size_t)8 * N_NODES * sizeof(int), stream);
    k_deg8<<<nEdgeBlocks, 256, 0, stream>>>(dst, deg8, rank);
    k_scan1<<<nScanBlocks + 6250, 256, 0, stream>>>(deg8, deg, offs, bsum, x, xb);
    k_offs8<<<nScanBlocks + 4, 256, 0, stream>>>(offs, bsum, deg8, offs, offs8,
                                                 Wl0, Wr0, Wl1, Wr1, Wt);
    k_place<<<nEdgeBlocks, 256, 0, stream>>>(src, rank, dst, offs8, csr);

    // layer 0: h = relu(aggr@Wl0 + x@Wr0 + b0) -> xb (in place, bf16)
    k_aggr_b<<<nAggrBlocks, 256, 0, stream>>>(xb, offs, deg, csr, aggrb);
    k_gemm_mfma<1, 1><<<nGemmBlocks, 256, 0, stream>>>(aggrb, xb, Wt_l0, Wt_r0, b0, xb);

    // layer 1: out = aggr_h@Wl1 + h@Wr1 + b1 -> d_out (fp32)
    k_aggr_b<<<nAggrBlocks, 256, 0, stream>>>(xb, offs, deg, csr, aggrb);
    k_gemm_mfma<0, 0><<<nGemmBlocks, 256, 0, stream>>>(aggrb, xb, Wt_l1, Wt_r1, b1, out);
}